// Round 13
// baseline (222.897 us; speedup 1.0000x reference)
//
#include <hip/hip_runtime.h>

typedef short  s16x8 __attribute__((ext_vector_type(8)));   // 8 bf16 bit patterns
typedef float  f32x4 __attribute__((ext_vector_type(4)));
typedef float  f32x2 __attribute__((ext_vector_type(2)));
typedef unsigned int u32;
typedef unsigned int u32x4 __attribute__((ext_vector_type(4)));
typedef unsigned short u16;

#define DEVI static __device__ __forceinline__

#if __has_builtin(__builtin_amdgcn_exp2f)
#define EXP2(v) __builtin_amdgcn_exp2f(v)   // raw v_exp_f32 (R11-proven)
#else
#define EXP2(v) exp2f(v)
#endif

constexpr int T_  = 128;
constexpr int F_  = 14;
constexpr int H_  = 64;
constexpr int BPB = 16;        // batch rows per block (grid 256, non-redundant)
constexpr int K_  = 4;         // timesteps per epoch (chunk)
constexpr int NCH = T_ / K_;   // 32 chunks

// LDS layout identical to R12 (sizes unchanged)
constexpr int HF_BYTES   = 2 * 2 * K_ * 2 * 64 * 16;     // 32768
constexpr int XBUF_BYTES = 2 * K_ * 64 * 16;             // 8192
constexpr int QBUF_BYTES = 2 * 3 * K_ * 4 * 64 * 16;     // 98304
constexpr int SMEM_BYTES = HF_BYTES + XBUF_BYTES + QBUF_BYTES;  // 139264

DEVI u16 f2bf(float f) {                     // RNE, one-time weight convert
  u32 u = __builtin_bit_cast(u32, f);
  u += 0x7fffu + ((u >> 16) & 1u);
  return (u16)(u >> 16);
}
DEVI u32 cvtpk(float a, float b) {           // HW packed bf16 cvt (RNE)
  u32 r;
  asm("v_cvt_pk_bf16_f32 %0, %1, %2" : "=v"(r) : "v"(a), "v"(b));
  return r;
}
// B-frag kt from tanh'd acc tiles: elements 0-3 = tile kt, 4-7 = tile kt+2
DEVI s16x8 packfrag(const f32x4& a, const f32x4& b) {
  u32x4 p;
  p[0] = cvtpk(a[0], a[1]); p[1] = cvtpk(a[2], a[3]);
  p[2] = cvtpk(b[0], b[1]); p[3] = cvtpk(b[2], b[3]);
  return __builtin_bit_cast(s16x8, p);
}
// tanh; mul/add/fma as packed fp32 (bit-identical to scalar), trans scalar.
DEVI f32x4 tanh4(const f32x4& v) {
  const f32x4 kC = -2.8853900817779268f;
  f32x4 t = v * kC;
  f32x4 e;
  e[0] = EXP2(t[0]); e[1] = EXP2(t[1]);
  e[2] = EXP2(t[2]); e[3] = EXP2(t[3]);
  const f32x4 kOne = 1.0f;
  f32x4 d = e + kOne;
  f32x4 r;
  r[0] = __builtin_amdgcn_rcpf(d[0]); r[1] = __builtin_amdgcn_rcpf(d[1]);
  r[2] = __builtin_amdgcn_rcpf(d[2]); r[3] = __builtin_amdgcn_rcpf(d[3]);
  const f32x4 kTwo = 2.0f, kNegOne = -1.0f;
  return __builtin_elementwise_fma(kTwo, r, kNegOne);
}
DEVI f32x4 MFMA(s16x8 a, s16x8 b, f32x4 c) {
  return __builtin_amdgcn_mfma_f32_16x16x32_bf16(a, b, c, 0, 0, 0);
}
DEVI s16x8 ldrow8(const float* p) {          // 8 contiguous fp32 -> bf16 A-frag
  const f32x4 a = ((const f32x4*)p)[0];
  const f32x4 b = ((const f32x4*)p)[1];
  s16x8 r;
  r[0] = (short)f2bf(a[0]); r[1] = (short)f2bf(a[1]);
  r[2] = (short)f2bf(a[2]); r[3] = (short)f2bf(a[3]);
  r[4] = (short)f2bf(b[0]); r[5] = (short)f2bf(b[1]);
  r[6] = (short)f2bf(b[2]); r[7] = (short)f2bf(b[3]);
  return r;
}

// R13: fuse the three recurrence waves into ONE wave (B012) for in-wave ILP.
// R12 analysis: the gating B wave is ~75% stalled on its serial chain
// (MFMA->MFMA->tanh->pack) and its light A partner can't fill the gaps
// (R10's symmetric heavy pairing measured 23% better per unit-step).  The
// three layers' recurrences are INDEPENDENT at step level (different,
// already-buffered chunks) -> one wave running all three chains gets 3-way
// ILP: each chain's latency is hidden by the other two chains' issue.
// 5 waves (320 thr): wv0=B012, wv1=P, wv2=A0, wv3=A1, wv4=A2.
// Schedule (re-derived, 1 barrier/epoch, all parities >=1 barrier apart):
//   A(l)@e: chunk e-2l   reads xbuf[wb] (l=0) / hf[wb][l-1] -> qbuf[wb][l]
//   B  @e: layer l chunk e-1-2l, reads qbuf[rbuf][l], writes hf[rbuf... 
//          (parity (e-1-2l)&1 = rbuf) [l<2]
//   P  @e: stages chunk e+1 -> xbuf[(e+1)&1]
// Steady epochs (e in [5,NCH]) use a branch-free 3-layer body so the
// compiler can interleave the chains.  Per-layer math is R12-VERBATIM ->
// absmax must be exactly 5.859375e-3.
__global__ __launch_bounds__(320, 1) void rnn_ck(
    const float* __restrict__ x,
    const float* __restrict__ Wih0, const float* __restrict__ Whh0,
    const float* __restrict__ bih0, const float* __restrict__ bhh0,
    const float* __restrict__ Wih1, const float* __restrict__ Whh1,
    const float* __restrict__ bih1, const float* __restrict__ bhh1,
    const float* __restrict__ Wih2, const float* __restrict__ Whh2,
    const float* __restrict__ bih2, const float* __restrict__ bhh2,
    const float* __restrict__ fc1w, const float* __restrict__ fc1b,
    const float* __restrict__ fc2w, const float* __restrict__ fc2b,
    float* __restrict__ out)
{
  extern __shared__ __align__(16) char smem[];
  // hf[par][layer01][k][frag][lane]; xbuf[par][k][lane]; qbuf[par][layer][k][tile][lane]
  u32x4 (*hf)[2][K_][2][64]   = (u32x4 (*)[2][K_][2][64])smem;
  u32x4 (*xbuf)[K_][64]       = (u32x4 (*)[K_][64])(smem + HF_BYTES);
  f32x4 (*qbuf)[3][K_][4][64] = (f32x4 (*)[3][K_][4][64])(smem + HF_BYTES + XBUF_BYTES);

  const int tid  = threadIdx.x;
  const int wv   = tid >> 6;
  const int lane = tid & 63;
  const int g    = lane >> 4;
  const int m    = lane & 15;
  const int b0   = blockIdx.x * BPB;

  f32x4 z4; z4[0] = 0.f; z4[1] = 0.f; z4[2] = 0.f; z4[3] = 0.f;
  s16x8 zf;
  #pragma unroll
  for (int i = 0; i < 8; i++) zf[i] = 0;

  // ---- role weights ----
  // B012 (wv0): Whh for all 3 layers (24 frags, 96 VGPR)
  s16x8 Ah[3][4][2];
  // A waves: own layer's input-side weights + bias sum
  s16x8 Ax[4], Ai[4][2];
  f32x4 bc[4];
  if (wv == 0) {
    const float* Whs[3] = {Whh0, Whh1, Whh2};
    #pragma unroll
    for (int l = 0; l < 3; l++) {
      #pragma unroll
      for (int n = 0; n < 4; n++) {
        const int Lr = 32 * (n & 1) + 8 * (m >> 2) + 4 * (n >> 1) + (m & 3);
        Ah[l][n][0] = ldrow8(Whs[l] + Lr * H_ + 8 * g);
        Ah[l][n][1] = ldrow8(Whs[l] + Lr * H_ + 32 + 8 * g);
      }
    }
  } else if (wv >= 2) {
    const int al = wv - 2;                    // A-layer 0..2
    const float* Wi = (al == 1) ? Wih1 : Wih2;
    const float* bi = (al == 0) ? bih0 : (al == 1) ? bih1 : bih2;
    const float* bh = (al == 0) ? bhh0 : (al == 1) ? bhh1 : bhh2;
    #pragma unroll
    for (int n = 0; n < 4; n++) {
      const int Lr = 32 * (n & 1) + 8 * (m >> 2) + 4 * (n >> 1) + (m & 3);
      if (al == 0) {                          // input side 64x14, pad K to 32
        s16x8 r;
        #pragma unroll
        for (int j2 = 0; j2 < 8; j2++) {
          const int kk = 8 * g + j2;
          r[j2] = (kk < F_) ? (short)f2bf(Wih0[Lr * F_ + kk]) : (short)0;
        }
        Ax[n] = r;
      } else {
        Ai[n][0] = ldrow8(Wi + Lr * H_ + 8 * g);
        Ai[n][1] = ldrow8(Wi + Lr * H_ + 32 + 8 * g);
      }
      const int Lb = 32 * (n & 1) + 8 * g + 4 * (n >> 1);
      bc[n] = *(const f32x4*)(bi + Lb) + *(const f32x4*)(bh + Lb);
    }
  }

  // ---- B012 state: per-layer h frags, h(-1)=0; layer-2 fp32 h2 ----
  s16x8 F[3][2];
  #pragma unroll
  for (int l = 0; l < 3; l++) { F[l][0] = zf; F[l][1] = zf; }
  f32x4 h2v[4];
  #pragma unroll
  for (int n = 0; n < 4; n++) h2v[n] = z4;

  // ---- x producer helpers (wv1) ----
  const float* xrow = x + (size_t)(b0 + m) * T_ * F_;
  auto ldraw = [&](int t, f32x4& ra, f32x4& rb) {    // R8-proven float2 loads
    const float* p = xrow + t * F_;
    if (g == 0) {
      f32x2 p0 = *(const f32x2*)(p),     p1 = *(const f32x2*)(p + 2);
      f32x2 p2 = *(const f32x2*)(p + 4), p3 = *(const f32x2*)(p + 6);
      ra[0] = p0[0]; ra[1] = p0[1]; ra[2] = p1[0]; ra[3] = p1[1];
      rb[0] = p2[0]; rb[1] = p2[1]; rb[2] = p3[0]; rb[3] = p3[1];
    } else if (g == 1) {
      f32x2 p4 = *(const f32x2*)(p + 8), p5 = *(const f32x2*)(p + 10);
      f32x2 p6 = *(const f32x2*)(p + 12);
      ra[0] = p4[0]; ra[1] = p4[1]; ra[2] = p5[0]; ra[3] = p5[1];
      rb[0] = p6[0]; rb[1] = p6[1]; rb[2] = 0.f;   rb[3] = 0.f;
    } else {
      ra = z4; rb = z4;
    }
  };
  auto cvtraw = [&](const f32x4& ra, const f32x4& rb) -> s16x8 {
    u32x4 p;
    p[0] = cvtpk(ra[0], ra[1]); p[1] = cvtpk(ra[2], ra[3]);
    p[2] = cvtpk(rb[0], rb[1]); p[3] = cvtpk(rb[2], rb[3]);
    return __builtin_bit_cast(s16x8, p);
  };
  auto stage4 = [&](int par, int t0) {       // one chunk (4 timesteps) -> xbuf
    f32x4 ra[K_], rb[K_];
    #pragma unroll
    for (int k = 0; k < K_; k++) ldraw(t0 + k, ra[k], rb[k]);
    #pragma unroll
    for (int k = 0; k < K_; k++)
      xbuf[par][k][lane] = __builtin_bit_cast(u32x4, cvtraw(ra[k], rb[k]));
  };

  // ---- B012 step body: layer l, step kk (both compile-time after unroll),
  //      chunk cl (wave-uniform).  R12-verbatim chain. ----
  auto stepL = [&](int l, int kk, int cl, int rbuf) {
    const f32x4 qc0 = qbuf[rbuf][l][kk][0][lane];
    const f32x4 qc1 = qbuf[rbuf][l][kk][1][lane];
    const f32x4 qc2 = qbuf[rbuf][l][kk][2][lane];
    const f32x4 qc3 = qbuf[rbuf][l][kk][3][lane];
    f32x4 p[4];
    p[0] = MFMA(Ah[l][0][0], F[l][0], qc0);
    p[2] = MFMA(Ah[l][2][0], F[l][0], qc2);
    p[1] = MFMA(Ah[l][1][0], F[l][0], qc1);
    p[3] = MFMA(Ah[l][3][0], F[l][0], qc3);
    p[0] = MFMA(Ah[l][0][1], F[l][1], p[0]);
    p[2] = MFMA(Ah[l][2][1], F[l][1], p[2]);
    p[1] = MFMA(Ah[l][1][1], F[l][1], p[1]);
    p[3] = MFMA(Ah[l][3][1], F[l][1], p[3]);

    f32x4 hv0 = tanh4(p[0]);
    f32x4 hv2 = tanh4(p[2]);
    F[l][0] = packfrag(hv0, hv2);
    f32x4 hv1 = tanh4(p[1]);
    f32x4 hv3 = tanh4(p[3]);
    F[l][1] = packfrag(hv1, hv3);

    if (l < 2) {
      hf[cl & 1][l][kk][0][lane] = __builtin_bit_cast(u32x4, F[l][0]);
      hf[cl & 1][l][kk][1][lane] = __builtin_bit_cast(u32x4, F[l][1]);
    } else if (cl == NCH - 1 && kk == K_ - 1) {
      h2v[0] = hv0; h2v[1] = hv1;            // fp32 h2 for head
      h2v[2] = hv2; h2v[3] = hv3;
    }
  };

  // ---- prologue: producer stages chunk 0 into xbuf[0] ----
  if (wv == 1) stage4(0, 0);
  __syncthreads();

  // ---- main loop: ONE barrier per epoch; e = 0..NCH+4 (37 epochs) ----
  #pragma unroll 1
  for (int e = 0; e < NCH + 5; e++) {
    const int wb = e & 1, rbuf = wb ^ 1;

    if (wv == 0) {
      // B012: layer l handles chunk e-1-2l
      const int c0 = e - 1, c1 = e - 3, c2 = e - 5;
      if (e >= 5 && e <= NCH) {
        // steady path: all three layers active, branch-free -> ILP
        #pragma unroll
        for (int kk = 0; kk < K_; kk++) {
          stepL(0, kk, c0, rbuf);
          stepL(1, kk, c1, rbuf);
          stepL(2, kk, c2, rbuf);
        }
      } else {
        const bool a0 = (c0 >= 0) && (c0 < NCH);
        const bool a1 = (c1 >= 0) && (c1 < NCH);
        const bool a2 = (c2 >= 0) && (c2 < NCH);
        #pragma unroll
        for (int kk = 0; kk < K_; kk++) {
          if (a0) stepL(0, kk, c0, rbuf);
          if (a1) stepL(1, kk, c1, rbuf);
          if (a2) stepL(2, kk, c2, rbuf);
        }
      }
    } else if (wv == 1) {
      // producer: stage chunk e+1 into xbuf[(e+1)&1]
      if (e <= NCH - 2) stage4(rbuf, (e + 1) * K_);
    } else {
      // A(l): chunk e-2l -> qbuf[wb][l]
      const int al = wv - 2;
      const int c  = e - 2 * al;
      if (c >= 0 && c < NCH) {
        if (al == 0) {
          #pragma unroll
          for (int k = 0; k < K_; k++) {
            const s16x8 xf = __builtin_bit_cast(s16x8, xbuf[wb][k][lane]);
            #pragma unroll
            for (int n = 0; n < 4; n++)
              qbuf[wb][0][k][n][lane] = MFMA(Ax[n], xf, bc[n]);
          }
        } else {
          #pragma unroll
          for (int k = 0; k < K_; k++) {
            const s16x8 P0 = __builtin_bit_cast(s16x8, hf[wb][al - 1][k][0][lane]);
            const s16x8 P1 = __builtin_bit_cast(s16x8, hf[wb][al - 1][k][1][lane]);
            f32x4 q[4];
            #pragma unroll
            for (int n = 0; n < 4; n++) q[n] = MFMA(Ai[n][0], P0, bc[n]);
            #pragma unroll
            for (int n = 0; n < 4; n++) q[n] = MFMA(Ai[n][1], P1, q[n]);
            #pragma unroll
            for (int n = 0; n < 4; n++) qbuf[wb][al][k][n][lane] = q[n];
          }
        }
      }
    }
    __syncthreads();   // single epoch-granular barrier (R12-proven protocol)
  }

  // ---- FC head: wv0 holds h2v; un-permute via LDS overlay, then compute ----
  float (*h2l)[68] = (float (*)[68])smem;
  if (wv == 0) {
    #pragma unroll
    for (int n = 0; n < 4; n++) {
      const int Lb = 32 * (n & 1) + 8 * g + 4 * (n >> 1);
      *(f32x4*)&h2l[m][Lb] = h2v[n];
    }
  }
  __syncthreads();

  if (wv == 0) {
    float hr[64];
    #pragma unroll
    for (int q = 0; q < 16; q++) {
      f32x4 v = *(const f32x4*)&h2l[m][4 * q];
      hr[4 * q + 0] = v[0]; hr[4 * q + 1] = v[1];
      hr[4 * q + 2] = v[2]; hr[4 * q + 3] = v[3];
    }
    float acc2 = 0.f;
    #pragma unroll
    for (int jj = 0; jj < 8; jj++) {
      const int jf = 8 * g + jj;
      float s = fc1b[jf];
      const f32x4* wp = (const f32x4*)(fc1w + jf * H_);
      #pragma unroll
      for (int kq = 0; kq < 16; kq++) {
        f32x4 wv2 = wp[kq];
        s += hr[4 * kq + 0] * wv2[0] + hr[4 * kq + 1] * wv2[1]
           + hr[4 * kq + 2] * wv2[2] + hr[4 * kq + 3] * wv2[3];
      }
      s = fmaxf(s, 0.f);
      acc2 += s * fc2w[jf];
    }
    acc2 += __shfl_xor(acc2, 16, 64);
    acc2 += __shfl_xor(acc2, 32, 64);
    if (lane < 16) out[b0 + m] = acc2 + fc2b[0];
  }
}

extern "C" void kernel_launch(void* const* d_in, const int* in_sizes, int n_in,
                              void* d_out, int out_size, void* d_ws, size_t ws_size,
                              hipStream_t stream) {
  const float* x    = (const float*)d_in[0];
  const float* Wih0 = (const float*)d_in[1];
  const float* Whh0 = (const float*)d_in[2];
  const float* bih0 = (const float*)d_in[3];
  const float* bhh0 = (const float*)d_in[4];
  const float* Wih1 = (const float*)d_in[5];
  const float* Whh1 = (const float*)d_in[6];
  const float* bih1 = (const float*)d_in[7];
  const float* bhh1 = (const float*)d_in[8];
  const float* Wih2 = (const float*)d_in[9];
  const float* Whh2 = (const float*)d_in[10];
  const float* bih2 = (const float*)d_in[11];
  const float* bhh2 = (const float*)d_in[12];
  const float* fc1w = (const float*)d_in[13];
  const float* fc1b = (const float*)d_in[14];
  const float* fc2w = (const float*)d_in[15];
  const float* fc2b = (const float*)d_in[16];

  static bool s_attr_set = false;
  if (!s_attr_set) {
    (void)hipFuncSetAttribute((const void*)rnn_ck,
                              hipFuncAttributeMaxDynamicSharedMemorySize,
                              SMEM_BYTES);
    s_attr_set = true;
  }

  rnn_ck<<<dim3(4096 / BPB), dim3(320), SMEM_BYTES, stream>>>(
      x, Wih0, Whh0, bih0, bhh0, Wih1, Whh1, bih1, bhh1,
      Wih2, Whh2, bih2, bhh2, fc1w, fc1b, fc2w, fc2b, (float*)d_out);
}

// Round 14
// 153.941 us; speedup vs baseline: 1.4479x; 1.4479x over previous
//
#include <hip/hip_runtime.h>

typedef short  s16x8 __attribute__((ext_vector_type(8)));   // 8 bf16 bit patterns
typedef float  f32x4 __attribute__((ext_vector_type(4)));
typedef float  f32x2 __attribute__((ext_vector_type(2)));
typedef unsigned int u32;
typedef unsigned int u32x4 __attribute__((ext_vector_type(4)));
typedef unsigned short u16;

#define DEVI static __device__ __forceinline__

#if __has_builtin(__builtin_amdgcn_exp2f)
#define EXP2(v) __builtin_amdgcn_exp2f(v)   // raw v_exp_f32 (R11-proven)
#else
#define EXP2(v) exp2f(v)
#endif

constexpr int T_  = 128;
constexpr int F_  = 14;
constexpr int H_  = 64;
constexpr int BPB = 16;        // batch rows per block (grid 256, non-redundant)
constexpr int K_  = 4;         // timesteps per epoch (chunk)
constexpr int NCH = T_ / K_;   // 32 chunks

// LDS layout identical to R12 (sizes unchanged)
constexpr int HF_BYTES   = 2 * 2 * K_ * 2 * 64 * 16;     // 32768
constexpr int XBUF_BYTES = 2 * K_ * 64 * 16;             // 8192
constexpr int QBUF_BYTES = 2 * 3 * K_ * 4 * 64 * 16;     // 98304
constexpr int SMEM_BYTES = HF_BYTES + XBUF_BYTES + QBUF_BYTES;  // 139264

DEVI u16 f2bf(float f) {                     // RNE, one-time weight convert
  u32 u = __builtin_bit_cast(u32, f);
  u += 0x7fffu + ((u >> 16) & 1u);
  return (u16)(u >> 16);
}
DEVI u32 cvtpk(float a, float b) {           // HW packed bf16 cvt (RNE)
  u32 r;
  asm("v_cvt_pk_bf16_f32 %0, %1, %2" : "=v"(r) : "v"(a), "v"(b));
  return r;
}
// B-frag kt from tanh'd acc tiles: elements 0-3 = tile kt, 4-7 = tile kt+2
DEVI s16x8 packfrag(const f32x4& a, const f32x4& b) {
  u32x4 p;
  p[0] = cvtpk(a[0], a[1]); p[1] = cvtpk(a[2], a[3]);
  p[2] = cvtpk(b[0], b[1]); p[3] = cvtpk(b[2], b[3]);
  return __builtin_bit_cast(s16x8, p);
}
// tanh; mul/add/fma as packed fp32 (bit-identical to scalar), trans scalar.
DEVI f32x4 tanh4(const f32x4& v) {
  const f32x4 kC = -2.8853900817779268f;
  f32x4 t = v * kC;
  f32x4 e;
  e[0] = EXP2(t[0]); e[1] = EXP2(t[1]);
  e[2] = EXP2(t[2]); e[3] = EXP2(t[3]);
  const f32x4 kOne = 1.0f;
  f32x4 d = e + kOne;
  f32x4 r;
  r[0] = __builtin_amdgcn_rcpf(d[0]); r[1] = __builtin_amdgcn_rcpf(d[1]);
  r[2] = __builtin_amdgcn_rcpf(d[2]); r[3] = __builtin_amdgcn_rcpf(d[3]);
  const f32x4 kTwo = 2.0f, kNegOne = -1.0f;
  return __builtin_elementwise_fma(kTwo, r, kNegOne);
}
DEVI f32x4 MFMA(s16x8 a, s16x8 b, f32x4 c) {
  return __builtin_amdgcn_mfma_f32_16x16x32_bf16(a, b, c, 0, 0, 0);
}
DEVI s16x8 ldrow8(const float* p) {          // 8 contiguous fp32 -> bf16 A-frag
  const f32x4 a = ((const f32x4*)p)[0];
  const f32x4 b = ((const f32x4*)p)[1];
  s16x8 r;
  r[0] = (short)f2bf(a[0]); r[1] = (short)f2bf(a[1]);
  r[2] = (short)f2bf(a[2]); r[3] = (short)f2bf(a[3]);
  r[4] = (short)f2bf(b[0]); r[5] = (short)f2bf(b[1]);
  r[6] = (short)f2bf(b[2]); r[7] = (short)f2bf(b[3]);
  return r;
}

// R14 = R12 (proven best, 70.7us rocprof) + scheduling-only latency fixes.
// R13's 3-layer fusion spilled (VGPR capped 128, WRITE_SIZE 7.7MB) — reverted.
// R12 counters: B epoch 1117cy vs ~650cy chain+issue -> ~450cy is exposed
// latency from reads placed immediately before use.  THIS ROUND (no protocol
// or arithmetic change; absmax must stay exactly 5.859375e-3):
//  * B: chunk-top bulk prefetch of all 16 qbuf tiles into regs (counted
//    lgkmcnt waits; steps run register-resident)
//  * A: bulk prefetch of its 8 P0/P1 frags
//  * P: issue chunk e+1's global loads at epoch e, cvt+write at e+1 into the
//    SAME slot/parity as R12 (slot schedule untouched -> no race); HBM
//    latency gets a whole epoch to land.
// Roles/offsets/barriers are R12-VERBATIM:
//   wv0..2 = B(l): chunk e-(2l+2), reads qbuf[rbuf][l], writes hf[wb][l<2]
//   wv4..6 = A(l): chunk e-(2l+1), reads xbuf[rbuf]/hf[rbuf][l-1],
//            writes qbuf[wb][l]
//   wv3    = P: writes chunk e -> xbuf[wb] at epoch e (loads issued at e-1)
//   wv7    = idle (barriers only)
__global__ __launch_bounds__(512, 1) void rnn_ck(
    const float* __restrict__ x,
    const float* __restrict__ Wih0, const float* __restrict__ Whh0,
    const float* __restrict__ bih0, const float* __restrict__ bhh0,
    const float* __restrict__ Wih1, const float* __restrict__ Whh1,
    const float* __restrict__ bih1, const float* __restrict__ bhh1,
    const float* __restrict__ Wih2, const float* __restrict__ Whh2,
    const float* __restrict__ bih2, const float* __restrict__ bhh2,
    const float* __restrict__ fc1w, const float* __restrict__ fc1b,
    const float* __restrict__ fc2w, const float* __restrict__ fc2b,
    float* __restrict__ out)
{
  extern __shared__ __align__(16) char smem[];
  // hf[par][layer01][k][frag][lane]; xbuf[par][k][lane]; qbuf[par][layer][k][tile][lane]
  u32x4 (*hf)[2][K_][2][64]   = (u32x4 (*)[2][K_][2][64])smem;
  u32x4 (*xbuf)[K_][64]       = (u32x4 (*)[K_][64])(smem + HF_BYTES);
  f32x4 (*qbuf)[3][K_][4][64] = (f32x4 (*)[3][K_][4][64])(smem + HF_BYTES + XBUF_BYTES);

  const int tid  = threadIdx.x;
  const int wv   = tid >> 6;
  const int lane = tid & 63;
  const int g    = lane >> 4;
  const int m    = lane & 15;
  const int b0   = blockIdx.x * BPB;

  const bool isB = (wv < 3);
  const bool isP = (wv == 3);
  const bool isA = (wv >= 4 && wv < 7);
  const int  l   = isB ? wv : (wv - 4);   // layer for A/B roles (unused else)

  f32x4 z4; z4[0] = 0.f; z4[1] = 0.f; z4[2] = 0.f; z4[3] = 0.f;
  s16x8 zf;
  #pragma unroll
  for (int i = 0; i < 8; i++) zf[i] = 0;

  // ---- role weights (R3 Lr/Lb algebra, split by role) ----
  s16x8 Ax[4], Ai[4][2], Ah[4][2];
  f32x4 bc[4];
  if (isB) {
    const float* Wh = (l == 0) ? Whh0 : (l == 1) ? Whh1 : Whh2;
    #pragma unroll
    for (int n = 0; n < 4; n++) {
      const int Lr = 32 * (n & 1) + 8 * (m >> 2) + 4 * (n >> 1) + (m & 3);
      Ah[n][0] = ldrow8(Wh + Lr * H_ + 8 * g);
      Ah[n][1] = ldrow8(Wh + Lr * H_ + 32 + 8 * g);
    }
  } else if (isA) {
    const float* Wi = (l == 1) ? Wih1 : Wih2;          // l==0 uses Wih0 below
    const float* bi = (l == 0) ? bih0 : (l == 1) ? bih1 : bih2;
    const float* bh = (l == 0) ? bhh0 : (l == 1) ? bhh1 : bhh2;
    #pragma unroll
    for (int n = 0; n < 4; n++) {
      const int Lr = 32 * (n & 1) + 8 * (m >> 2) + 4 * (n >> 1) + (m & 3);
      if (l == 0) {                       // input side 64x14, zero-pad K to 32
        s16x8 r;
        #pragma unroll
        for (int j2 = 0; j2 < 8; j2++) {
          const int kk = 8 * g + j2;
          r[j2] = (kk < F_) ? (short)f2bf(Wih0[Lr * F_ + kk]) : (short)0;
        }
        Ax[n] = r;
      } else {
        Ai[n][0] = ldrow8(Wi + Lr * H_ + 8 * g);
        Ai[n][1] = ldrow8(Wi + Lr * H_ + 32 + 8 * g);
      }
      const int Lb = 32 * (n & 1) + 8 * g + 4 * (n >> 1);
      bc[n] = *(const f32x4*)(bi + Lb) + *(const f32x4*)(bh + Lb);
    }
  }

  // ---- B state: own-layer h frags, h(-1)=0 in registers ----
  s16x8 F[2];
  F[0] = zf; F[1] = zf;
  f32x4 h2v[4];
  #pragma unroll
  for (int n = 0; n < 4; n++) h2v[n] = z4;

  // ---- x producer helpers (wv3) ----
  const float* xrow = x + (size_t)(b0 + m) * T_ * F_;
  auto ldraw = [&](int t, f32x4& ra, f32x4& rb) {    // R8-proven float2 loads
    const float* p = xrow + t * F_;
    if (g == 0) {
      f32x2 p0 = *(const f32x2*)(p),     p1 = *(const f32x2*)(p + 2);
      f32x2 p2 = *(const f32x2*)(p + 4), p3 = *(const f32x2*)(p + 6);
      ra[0] = p0[0]; ra[1] = p0[1]; ra[2] = p1[0]; ra[3] = p1[1];
      rb[0] = p2[0]; rb[1] = p2[1]; rb[2] = p3[0]; rb[3] = p3[1];
    } else if (g == 1) {
      f32x2 p4 = *(const f32x2*)(p + 8), p5 = *(const f32x2*)(p + 10);
      f32x2 p6 = *(const f32x2*)(p + 12);
      ra[0] = p4[0]; ra[1] = p4[1]; ra[2] = p5[0]; ra[3] = p5[1];
      rb[0] = p6[0]; rb[1] = p6[1]; rb[2] = 0.f;   rb[3] = 0.f;
    } else {
      ra = z4; rb = z4;
    }
  };
  auto cvtraw = [&](const f32x4& ra, const f32x4& rb) -> s16x8 {
    u32x4 p;
    p[0] = cvtpk(ra[0], ra[1]); p[1] = cvtpk(ra[2], ra[3]);
    p[2] = cvtpk(rb[0], rb[1]); p[3] = cvtpk(rb[2], rb[3]);
    return __builtin_bit_cast(s16x8, p);
  };

  // P pipeline registers: raw x for the NEXT chunk, loaded one epoch ahead
  f32x4 pra[K_], prb[K_];

  // ---- prologue: stage chunk 0 (serial), then issue chunk 1's loads ----
  if (isP) {
    f32x4 ra[K_], rb[K_];
    #pragma unroll
    for (int k = 0; k < K_; k++) ldraw(k, ra[k], rb[k]);
    #pragma unroll
    for (int k = 0; k < K_; k++)
      xbuf[0][k][lane] = __builtin_bit_cast(u32x4, cvtraw(ra[k], rb[k]));
    #pragma unroll
    for (int k = 0; k < K_; k++) ldraw(K_ + k, pra[k], prb[k]);   // chunk 1
  }
  __syncthreads();

  // ---- main loop: 1 barrier/epoch; stage chain 1 epoch apart per hop ----
  #pragma unroll 1
  for (int e = 0; e < NCH + 6; e++) {
    const int wb = e & 1, rbuf = wb ^ 1;

    if (isP) {
      // cvt+write chunk e (loads issued at e-1) -> xbuf[wb]  (R12 slot sched)
      if (e >= 1 && e < NCH) {
        #pragma unroll
        for (int k = 0; k < K_; k++)
          xbuf[wb][k][lane] = __builtin_bit_cast(u32x4, cvtraw(pra[k], prb[k]));
        // issue chunk e+1's loads (consumed next epoch)
        if (e <= NCH - 2) {
          #pragma unroll
          for (int k = 0; k < K_; k++) ldraw((e + 1) * K_ + k, pra[k], prb[k]);
        }
      }
    } else if (isA) {
      const int c = e - (2 * l + 1);
      if (c >= 0 && c < NCH) {
        if (l == 0) {
          // bulk prefetch x frags, then compute
          s16x8 xr[K_];
          #pragma unroll
          for (int k = 0; k < K_; k++)
            xr[k] = __builtin_bit_cast(s16x8, xbuf[rbuf][k][lane]);
          #pragma unroll
          for (int k = 0; k < K_; k++) {
            #pragma unroll
            for (int n = 0; n < 4; n++)
              qbuf[wb][0][k][n][lane] = MFMA(Ax[n], xr[k], bc[n]);
          }
        } else {
          // bulk prefetch P0/P1 frags, then compute
          s16x8 P0r[K_], P1r[K_];
          #pragma unroll
          for (int k = 0; k < K_; k++) {
            P0r[k] = __builtin_bit_cast(s16x8, hf[rbuf][l - 1][k][0][lane]);
            P1r[k] = __builtin_bit_cast(s16x8, hf[rbuf][l - 1][k][1][lane]);
          }
          #pragma unroll
          for (int k = 0; k < K_; k++) {
            f32x4 q[4];
            #pragma unroll
            for (int n = 0; n < 4; n++) q[n] = MFMA(Ai[n][0], P0r[k], bc[n]);
            #pragma unroll
            for (int n = 0; n < 4; n++) q[n] = MFMA(Ai[n][1], P1r[k], q[n]);
            #pragma unroll
            for (int n = 0; n < 4; n++) qbuf[wb][l][k][n][lane] = q[n];
          }
        }
      }
    } else if (isB) {
      const int c = e - (2 * l + 2);
      if (c >= 0 && c < NCH) {
        // chunk-top bulk q prefetch: all 16 tiles -> regs (counted lgkmcnt)
        f32x4 qreg[K_][4];
        #pragma unroll
        for (int k = 0; k < K_; k++) {
          #pragma unroll
          for (int n = 0; n < 4; n++)
            qreg[k][n] = qbuf[rbuf][l][k][n][lane];
        }
        #pragma unroll
        for (int k = 0; k < K_; k++) {
          // R12-verbatim p-chain: tiles 0,2 first so F[0] retires first
          f32x4 p[4];
          p[0] = MFMA(Ah[0][0], F[0], qreg[k][0]);
          p[2] = MFMA(Ah[2][0], F[0], qreg[k][2]);
          p[1] = MFMA(Ah[1][0], F[0], qreg[k][1]);
          p[3] = MFMA(Ah[3][0], F[0], qreg[k][3]);
          p[0] = MFMA(Ah[0][1], F[1], p[0]);
          p[2] = MFMA(Ah[2][1], F[1], p[2]);
          p[1] = MFMA(Ah[1][1], F[1], p[1]);
          p[3] = MFMA(Ah[3][1], F[1], p[3]);

          f32x4 hv0 = tanh4(p[0]);
          f32x4 hv2 = tanh4(p[2]);
          F[0] = packfrag(hv0, hv2);
          f32x4 hv1 = tanh4(p[1]);
          f32x4 hv3 = tanh4(p[3]);
          F[1] = packfrag(hv1, hv3);

          if (l < 2) {
            hf[wb][l][k][0][lane] = __builtin_bit_cast(u32x4, F[0]);
            hf[wb][l][k][1][lane] = __builtin_bit_cast(u32x4, F[1]);
          } else if (c == NCH - 1 && k == K_ - 1) {
            h2v[0] = hv0; h2v[1] = hv1;    // fp32 h2 for head
            h2v[2] = hv2; h2v[3] = hv3;
          }
        }
      }
    }
    __syncthreads();   // single epoch-granular barrier (R12-proven protocol)
  }

  // ---- FC head: h2l overlays dead smem; B2 (wv2) un-permutes, B0 computes --
  float (*h2l)[68] = (float (*)[68])smem;
  if (wv == 2) {
    #pragma unroll
    for (int n = 0; n < 4; n++) {
      const int Lb = 32 * (n & 1) + 8 * g + 4 * (n >> 1);
      *(f32x4*)&h2l[m][Lb] = h2v[n];
    }
  }
  __syncthreads();

  if (wv == 0) {
    float hr[64];
    #pragma unroll
    for (int q = 0; q < 16; q++) {
      f32x4 v = *(const f32x4*)&h2l[m][4 * q];
      hr[4 * q + 0] = v[0]; hr[4 * q + 1] = v[1];
      hr[4 * q + 2] = v[2]; hr[4 * q + 3] = v[3];
    }
    float acc2 = 0.f;
    #pragma unroll
    for (int jj = 0; jj < 8; jj++) {
      const int jf = 8 * g + jj;
      float s = fc1b[jf];
      const f32x4* wp = (const f32x4*)(fc1w + jf * H_);
      #pragma unroll
      for (int kq = 0; kq < 16; kq++) {
        f32x4 wv2 = wp[kq];
        s += hr[4 * kq + 0] * wv2[0] + hr[4 * kq + 1] * wv2[1]
           + hr[4 * kq + 2] * wv2[2] + hr[4 * kq + 3] * wv2[3];
      }
      s = fmaxf(s, 0.f);
      acc2 += s * fc2w[jf];
    }
    acc2 += __shfl_xor(acc2, 16, 64);
    acc2 += __shfl_xor(acc2, 32, 64);
    if (lane < 16) out[b0 + m] = acc2 + fc2b[0];
  }
}

extern "C" void kernel_launch(void* const* d_in, const int* in_sizes, int n_in,
                              void* d_out, int out_size, void* d_ws, size_t ws_size,
                              hipStream_t stream) {
  const float* x    = (const float*)d_in[0];
  const float* Wih0 = (const float*)d_in[1];
  const float* Whh0 = (const float*)d_in[2];
  const float* bih0 = (const float*)d_in[3];
  const float* bhh0 = (const float*)d_in[4];
  const float* Wih1 = (const float*)d_in[5];
  const float* Whh1 = (const float*)d_in[6];
  const float* bih1 = (const float*)d_in[7];
  const float* bhh1 = (const float*)d_in[8];
  const float* Wih2 = (const float*)d_in[9];
  const float* Whh2 = (const float*)d_in[10];
  const float* bih2 = (const float*)d_in[11];
  const float* bhh2 = (const float*)d_in[12];
  const float* fc1w = (const float*)d_in[13];
  const float* fc1b = (const float*)d_in[14];
  const float* fc2w = (const float*)d_in[15];
  const float* fc2b = (const float*)d_in[16];

  static bool s_attr_set = false;
  if (!s_attr_set) {
    (void)hipFuncSetAttribute((const void*)rnn_ck,
                              hipFuncAttributeMaxDynamicSharedMemorySize,
                              SMEM_BYTES);
    s_attr_set = true;
  }

  rnn_ck<<<dim3(4096 / BPB), dim3(512), SMEM_BYTES, stream>>>(
      x, Wih0, Whh0, bih0, bhh0, Wih1, Whh1, bih1, bhh1,
      Wih2, Whh2, bih2, bhh2, fc1w, fc1b, fc2w, fc2b, (float*)d_out);
}